// Round 2
// baseline (1455.339 us; speedup 1.0000x reference)
//
#include <hip/hip_runtime.h>

#define D 8

__global__ void zero_kernel(float* __restrict__ node_out, int n_node_f,
                            float* __restrict__ counts, int n_counts) {
    int stride = gridDim.x * blockDim.x;
    int tid = blockIdx.x * blockDim.x + threadIdx.x;
    for (int i = tid; i < n_node_f; i += stride) node_out[i] = 0.0f;
    for (int i = tid; i < n_counts; i += stride) counts[i] = 0.0f;
}

__global__ void edge_kernel(const float4* __restrict__ x4,
                            const int* __restrict__ src_idx,
                            const int* __restrict__ dst_idx,
                            const float4* __restrict__ ea4,
                            float4* __restrict__ out_edge4,
                            float* __restrict__ node_sums,
                            float* __restrict__ counts,
                            int n_edges) {
    int e = blockIdx.x * blockDim.x + threadIdx.x;
    if (e >= n_edges) return;

    int s = src_idx[e];
    int t = dst_idx[e];

    float4 xs0 = x4[(size_t)s * 2 + 0];
    float4 xs1 = x4[(size_t)s * 2 + 1];
    float4 xd0 = x4[(size_t)t * 2 + 0];
    float4 xd1 = x4[(size_t)t * 2 + 1];
    float4 a0  = ea4[(size_t)e * 2 + 0];
    float4 a1  = ea4[(size_t)e * 2 + 1];

    float4 d0, d1;
    d0.x = (xd0.x - xs0.x) / a0.x;
    d0.y = (xd0.y - xs0.y) / a0.y;
    d0.z = (xd0.z - xs0.z) / a0.z;
    d0.w = (xd0.w - xs0.w) / a0.w;
    d1.x = (xd1.x - xs1.x) / a1.x;
    d1.y = (xd1.y - xs1.y) / a1.y;
    d1.z = (xd1.z - xs1.z) / a1.z;
    d1.w = (xd1.w - xs1.w) / a1.w;

    out_edge4[(size_t)e * 2 + 0] = d0;
    out_edge4[(size_t)e * 2 + 1] = d1;

    float* sp = node_sums + (size_t)t * D;
    atomicAdd(sp + 0, d0.x);
    atomicAdd(sp + 1, d0.y);
    atomicAdd(sp + 2, d0.z);
    atomicAdd(sp + 3, d0.w);
    atomicAdd(sp + 4, d1.x);
    atomicAdd(sp + 5, d1.y);
    atomicAdd(sp + 6, d1.z);
    atomicAdd(sp + 7, d1.w);
    atomicAdd(counts + t, 1.0f);
}

__global__ void node_kernel(float4* __restrict__ node4,
                            const float* __restrict__ counts,
                            int n_nodes) {
    int n = blockIdx.x * blockDim.x + threadIdx.x;
    if (n >= n_nodes) return;

    float inv = 1.0f / fmaxf(counts[n], 1.0f);

    float4 s0 = node4[(size_t)n * 2 + 0];
    float4 s1 = node4[(size_t)n * 2 + 1];
    s0.x *= inv; s0.y *= inv; s0.z *= inv; s0.w *= inv;
    s1.x *= inv; s1.y *= inv; s1.z *= inv; s1.w *= inv;
    node4[(size_t)n * 2 + 0] = s0;
    node4[(size_t)n * 2 + 1] = s1;
}

extern "C" void kernel_launch(void* const* d_in, const int* in_sizes, int n_in,
                              void* d_out, int out_size, void* d_ws, size_t ws_size,
                              hipStream_t stream) {
    const float* x  = (const float*)d_in[0];      // [n_nodes, 8] fp32
    const int*   ei = (const int*)d_in[1];        // [2, n_edges] int32 (harness delivers ints as int32)
    const float* ea = (const float*)d_in[2];      // [n_edges, 8] fp32

    const int n_nodes = in_sizes[0] / D;
    const int n_edges = in_sizes[2] / D;

    const int* src_idx = ei;                      // edge_index[0]
    const int* dst_idx = ei + n_edges;            // edge_index[1]

    float* out_node = (float*)d_out;                       // [n_nodes, 8] — used as sums accumulator
    float* out_edge = out_node + (size_t)n_nodes * D;      // [n_edges, 8]

    float* counts = (float*)d_ws;                          // [n_nodes] — only 400 KB of ws

    // 1) zero the node-output accumulator + counts (d_out/d_ws are NOT
    //    re-poisoned between timed replays, so this must happen every call)
    {
        int n = n_nodes * D;
        int blocks = (n + 255) / 256;
        if (blocks > 2048) blocks = 2048;
        zero_kernel<<<blocks, 256, 0, stream>>>(out_node, n, counts, n_nodes);
    }

    // 2) per-edge: edge_deriv + scatter-add into out_node
    {
        int blocks = (n_edges + 255) / 256;
        edge_kernel<<<blocks, 256, 0, stream>>>(
            (const float4*)x, src_idx, dst_idx, (const float4*)ea,
            (float4*)out_edge, out_node, counts, n_edges);
    }

    // 3) per-node: divide by count in place
    {
        int blocks = (n_nodes + 255) / 256;
        node_kernel<<<blocks, 256, 0, stream>>>(
            (float4*)out_node, counts, n_nodes);
    }
}

// Round 3
// 317.503 us; speedup vs baseline: 4.5837x; 4.5837x over previous
//
#include <hip/hip_runtime.h>

#define D 8
#define BSH 8              // bucket = dst >> 8 (256 nodes per bucket)
#define BMASK 255
#define NBMAX 512          // max buckets supported by fast path
#define EPB 4096           // edges per block in phase A
#define RREP 4             // replica workers per bucket in phase B
#define PSZ (256 * 9)      // floats per partial (256 nodes x (8 sums + count))

// ---------------- fast path ----------------

__global__ void zero_cursors_kernel(unsigned* __restrict__ cur, int nb) {
    int i = blockIdx.x * blockDim.x + threadIdx.x;
    if (i < nb) cur[i] = 0u;
}

__global__ __launch_bounds__(256) void edge_phase_kernel(
    const float4* __restrict__ x4,
    const int* __restrict__ src_idx,
    const int* __restrict__ dst_idx,
    const float4* __restrict__ ea4,
    float4* __restrict__ out_edge4,
    unsigned* __restrict__ cursors,
    unsigned* __restrict__ pairs,
    int n_edges, int nb, int cap)
{
    __shared__ unsigned hist[NBMAX];
    __shared__ unsigned base[NBMAX];
    __shared__ unsigned cur[NBMAX];
    for (int b = threadIdx.x; b < nb; b += 256) { hist[b] = 0u; cur[b] = 0u; }
    __syncthreads();

    const int start = blockIdx.x * EPB;

    // pass 1: compute edge_deriv, write it, build LDS histogram of buckets
    for (int i = threadIdx.x; i < EPB; i += 256) {
        int e = start + i;
        if (e >= n_edges) break;
        int s = src_idx[e];
        int t = dst_idx[e];
        float4 xs0 = x4[(size_t)s * 2 + 0];
        float4 xs1 = x4[(size_t)s * 2 + 1];
        float4 xd0 = x4[(size_t)t * 2 + 0];
        float4 xd1 = x4[(size_t)t * 2 + 1];
        float4 a0  = ea4[(size_t)e * 2 + 0];
        float4 a1  = ea4[(size_t)e * 2 + 1];
        float4 d0, d1;
        d0.x = (xd0.x - xs0.x) / a0.x;
        d0.y = (xd0.y - xs0.y) / a0.y;
        d0.z = (xd0.z - xs0.z) / a0.z;
        d0.w = (xd0.w - xs0.w) / a0.w;
        d1.x = (xd1.x - xs1.x) / a1.x;
        d1.y = (xd1.y - xs1.y) / a1.y;
        d1.z = (xd1.z - xs1.z) / a1.z;
        d1.w = (xd1.w - xs1.w) / a1.w;
        out_edge4[(size_t)e * 2 + 0] = d0;
        out_edge4[(size_t)e * 2 + 1] = d1;
        atomicAdd(&hist[t >> BSH], 1u);
    }
    __syncthreads();

    // reserve contiguous space in each bucket's region (1 device atomic per (block,bucket))
    for (int b = threadIdx.x; b < nb; b += 256)
        base[b] = hist[b] ? atomicAdd(&cursors[b], hist[b]) : 0u;
    __syncthreads();

    // pass 2: scatter packed records (eid<<8 | local-node)
    for (int i = threadIdx.x; i < EPB; i += 256) {
        int e = start + i;
        if (e >= n_edges) break;
        int t = dst_idx[e];               // L1-hot re-read
        int b = t >> BSH;
        unsigned p = base[b] + atomicAdd(&cur[b], 1u);
        if (p < (unsigned)cap)
            pairs[(size_t)b * cap + p] = ((unsigned)e << BSH) | (unsigned)(t & BMASK);
    }
}

__global__ __launch_bounds__(256) void bucket_reduce_kernel(
    const unsigned* __restrict__ cursors,
    const unsigned* __restrict__ pairs,
    const float4* __restrict__ edge4,
    float* __restrict__ partials,
    int cap)
{
    __shared__ float acc[PSZ];
    for (int j = threadIdx.x; j < PSZ; j += 256) acc[j] = 0.0f;
    __syncthreads();

    const int b = blockIdx.x / RREP;
    const int r = blockIdx.x % RREP;
    int count = (int)cursors[b];
    if (count > cap) count = cap;
    const int s0 = (int)((long long)count * r / RREP);
    const int s1 = (int)((long long)count * (r + 1) / RREP);
    const unsigned* pb = pairs + (size_t)b * cap;

    for (int i = s0 + threadIdx.x; i < s1; i += 256) {
        unsigned pr  = pb[i];
        unsigned eid = pr >> BSH;
        unsigned loc = pr & BMASK;
        float4 d0 = edge4[(size_t)eid * 2 + 0];
        float4 d1 = edge4[(size_t)eid * 2 + 1];
        float* a = acc + loc * 9;
        atomicAdd(a + 0, d0.x);
        atomicAdd(a + 1, d0.y);
        atomicAdd(a + 2, d0.z);
        atomicAdd(a + 3, d0.w);
        atomicAdd(a + 4, d1.x);
        atomicAdd(a + 5, d1.y);
        atomicAdd(a + 6, d1.z);
        atomicAdd(a + 7, d1.w);
        atomicAdd(a + 8, 1.0f);
    }
    __syncthreads();

    float* out = partials + (size_t)blockIdx.x * PSZ;
    for (int j = threadIdx.x; j < PSZ; j += 256) out[j] = acc[j];
}

__global__ __launch_bounds__(256) void node_final_kernel(
    const float* __restrict__ partials,
    float4* __restrict__ out_node4,
    int n_nodes)
{
    int n = blockIdx.x * blockDim.x + threadIdx.x;
    if (n >= n_nodes) return;
    int b = n >> BSH, loc = n & BMASK;
    float s[9];
#pragma unroll
    for (int k = 0; k < 9; ++k) s[k] = 0.0f;
#pragma unroll
    for (int r = 0; r < RREP; ++r) {
        const float* p = partials + ((size_t)(b * RREP + r)) * PSZ + loc * 9;
#pragma unroll
        for (int k = 0; k < 9; ++k) s[k] += p[k];
    }
    float inv = 1.0f / fmaxf(s[8], 1.0f);
    float4 o0 = { s[0] * inv, s[1] * inv, s[2] * inv, s[3] * inv };
    float4 o1 = { s[4] * inv, s[5] * inv, s[6] * inv, s[7] * inv };
    out_node4[(size_t)n * 2 + 0] = o0;
    out_node4[(size_t)n * 2 + 1] = o1;
}

// ---------------- fallback path (proven round-2 atomic version) ----------------

__global__ void fb_zero_kernel(float* __restrict__ node_out, int n_node_f,
                               float* __restrict__ counts, int n_counts) {
    int stride = gridDim.x * blockDim.x;
    int tid = blockIdx.x * blockDim.x + threadIdx.x;
    for (int i = tid; i < n_node_f; i += stride) node_out[i] = 0.0f;
    for (int i = tid; i < n_counts; i += stride) counts[i] = 0.0f;
}

__global__ void fb_edge_kernel(const float4* __restrict__ x4,
                               const int* __restrict__ src_idx,
                               const int* __restrict__ dst_idx,
                               const float4* __restrict__ ea4,
                               float4* __restrict__ out_edge4,
                               float* __restrict__ node_sums,
                               float* __restrict__ counts,
                               int n_edges) {
    int e = blockIdx.x * blockDim.x + threadIdx.x;
    if (e >= n_edges) return;
    int s = src_idx[e];
    int t = dst_idx[e];
    float4 xs0 = x4[(size_t)s * 2 + 0];
    float4 xs1 = x4[(size_t)s * 2 + 1];
    float4 xd0 = x4[(size_t)t * 2 + 0];
    float4 xd1 = x4[(size_t)t * 2 + 1];
    float4 a0  = ea4[(size_t)e * 2 + 0];
    float4 a1  = ea4[(size_t)e * 2 + 1];
    float4 d0, d1;
    d0.x = (xd0.x - xs0.x) / a0.x;
    d0.y = (xd0.y - xs0.y) / a0.y;
    d0.z = (xd0.z - xs0.z) / a0.z;
    d0.w = (xd0.w - xs0.w) / a0.w;
    d1.x = (xd1.x - xs1.x) / a1.x;
    d1.y = (xd1.y - xs1.y) / a1.y;
    d1.z = (xd1.z - xs1.z) / a1.z;
    d1.w = (xd1.w - xs1.w) / a1.w;
    out_edge4[(size_t)e * 2 + 0] = d0;
    out_edge4[(size_t)e * 2 + 1] = d1;
    float* sp = node_sums + (size_t)t * D;
    atomicAdd(sp + 0, d0.x);
    atomicAdd(sp + 1, d0.y);
    atomicAdd(sp + 2, d0.z);
    atomicAdd(sp + 3, d0.w);
    atomicAdd(sp + 4, d1.x);
    atomicAdd(sp + 5, d1.y);
    atomicAdd(sp + 6, d1.z);
    atomicAdd(sp + 7, d1.w);
    atomicAdd(counts + t, 1.0f);
}

__global__ void fb_node_kernel(float4* __restrict__ node4,
                               const float* __restrict__ counts,
                               int n_nodes) {
    int n = blockIdx.x * blockDim.x + threadIdx.x;
    if (n >= n_nodes) return;
    float inv = 1.0f / fmaxf(counts[n], 1.0f);
    float4 s0 = node4[(size_t)n * 2 + 0];
    float4 s1 = node4[(size_t)n * 2 + 1];
    s0.x *= inv; s0.y *= inv; s0.z *= inv; s0.w *= inv;
    s1.x *= inv; s1.y *= inv; s1.z *= inv; s1.w *= inv;
    node4[(size_t)n * 2 + 0] = s0;
    node4[(size_t)n * 2 + 1] = s1;
}

// ---------------- launch ----------------

extern "C" void kernel_launch(void* const* d_in, const int* in_sizes, int n_in,
                              void* d_out, int out_size, void* d_ws, size_t ws_size,
                              hipStream_t stream) {
    const float* x  = (const float*)d_in[0];      // [n_nodes, 8] fp32
    const int*   ei = (const int*)d_in[1];        // [2, n_edges] int32
    const float* ea = (const float*)d_in[2];      // [n_edges, 8] fp32

    const int n_nodes = in_sizes[0] / D;
    const int n_edges = in_sizes[2] / D;

    const int* src_idx = ei;
    const int* dst_idx = ei + n_edges;

    float* out_node = (float*)d_out;
    float* out_edge = out_node + (size_t)n_nodes * D;

    const int nb = (n_nodes + 255) >> BSH;
    // capacity per bucket: 1.5x expected + slack
    int cap = (int)(((long long)n_edges / (nb > 0 ? nb : 1) + 256) * 3 / 2);

    size_t cursors_bytes  = ((size_t)nb * 4 + 255) & ~(size_t)255;
    size_t pairs_bytes    = ((size_t)nb * cap * 4 + 255) & ~(size_t)255;
    size_t partials_bytes = (size_t)nb * RREP * PSZ * 4;
    size_t need = cursors_bytes + pairs_bytes + partials_bytes;

    if (nb <= NBMAX && ws_size >= need) {
        unsigned* cursors  = (unsigned*)d_ws;
        unsigned* pairs    = (unsigned*)((char*)d_ws + cursors_bytes);
        float*    partials = (float*)((char*)d_ws + cursors_bytes + pairs_bytes);

        zero_cursors_kernel<<<(nb + 255) / 256, 256, 0, stream>>>(cursors, nb);

        int blocksA = (n_edges + EPB - 1) / EPB;
        edge_phase_kernel<<<blocksA, 256, 0, stream>>>(
            (const float4*)x, src_idx, dst_idx, (const float4*)ea,
            (float4*)out_edge, cursors, pairs, n_edges, nb, cap);

        bucket_reduce_kernel<<<nb * RREP, 256, 0, stream>>>(
            cursors, pairs, (const float4*)out_edge, partials, cap);

        node_final_kernel<<<(n_nodes + 255) / 256, 256, 0, stream>>>(
            partials, (float4*)out_node, n_nodes);
    } else {
        // fallback: direct-atomic version (needs only n_nodes*4 bytes of ws)
        float* counts = (float*)d_ws;
        {
            int n = n_nodes * D;
            int blocks = (n + 255) / 256;
            if (blocks > 2048) blocks = 2048;
            fb_zero_kernel<<<blocks, 256, 0, stream>>>(out_node, n, counts, n_nodes);
        }
        fb_edge_kernel<<<(n_edges + 255) / 256, 256, 0, stream>>>(
            (const float4*)x, src_idx, dst_idx, (const float4*)ea,
            (float4*)out_edge, out_node, counts, n_edges);
        fb_node_kernel<<<(n_nodes + 255) / 256, 256, 0, stream>>>(
            (float4*)out_node, counts, n_nodes);
    }
}

// Round 4
// 291.799 us; speedup vs baseline: 4.9875x; 1.0881x over previous
//
#include <hip/hip_runtime.h>

#define D 8
#define BSH 6              // bucket = dst >> 6 (64 nodes per bucket)
#define BMASK 63
#define NBMAX 1600         // max buckets supported by fast path
#define EPB 6250           // edges per block in phase A (3.2M/512)
#define APT 1024           // phase-A threads per block

// ---------------- fast path ----------------

__global__ void zero_cursors_kernel(unsigned* __restrict__ cur, int nb) {
    int i = blockIdx.x * blockDim.x + threadIdx.x;
    if (i < nb) cur[i] = 0u;
}

__global__ __launch_bounds__(APT) void edge_phase_kernel(
    const float4* __restrict__ x4,
    const int* __restrict__ src_idx,
    const int* __restrict__ dst_idx,
    const float4* __restrict__ ea4,
    float4* __restrict__ out_edge4,
    unsigned* __restrict__ cursors,
    unsigned* __restrict__ pairs,
    int n_edges, int nb, int cap)
{
    __shared__ unsigned hist[NBMAX];
    __shared__ unsigned base[NBMAX];
    __shared__ unsigned cur[NBMAX];
    __shared__ unsigned tld[EPB];     // cached dst per edge

    for (int b = threadIdx.x; b < nb; b += APT) { hist[b] = 0u; cur[b] = 0u; }
    __syncthreads();

    const int start = blockIdx.x * EPB;

    // pass 1: compute edge_deriv, write it, build LDS bucket histogram
    for (int i = threadIdx.x; i < EPB; i += APT) {
        int e = start + i;
        if (e >= n_edges) break;
        int s = src_idx[e];
        int t = dst_idx[e];
        tld[i] = (unsigned)t;
        float4 xs0 = x4[(size_t)s * 2 + 0];
        float4 xs1 = x4[(size_t)s * 2 + 1];
        float4 xd0 = x4[(size_t)t * 2 + 0];
        float4 xd1 = x4[(size_t)t * 2 + 1];
        float4 a0  = ea4[(size_t)e * 2 + 0];
        float4 a1  = ea4[(size_t)e * 2 + 1];
        float4 d0, d1;
        d0.x = (xd0.x - xs0.x) / a0.x;
        d0.y = (xd0.y - xs0.y) / a0.y;
        d0.z = (xd0.z - xs0.z) / a0.z;
        d0.w = (xd0.w - xs0.w) / a0.w;
        d1.x = (xd1.x - xs1.x) / a1.x;
        d1.y = (xd1.y - xs1.y) / a1.y;
        d1.z = (xd1.z - xs1.z) / a1.z;
        d1.w = (xd1.w - xs1.w) / a1.w;
        out_edge4[(size_t)e * 2 + 0] = d0;
        out_edge4[(size_t)e * 2 + 1] = d1;
        atomicAdd(&hist[t >> BSH], 1u);
    }
    __syncthreads();

    // reserve contiguous space per bucket (1 device atomic per (block,bucket))
    for (int b = threadIdx.x; b < nb; b += APT)
        base[b] = hist[b] ? atomicAdd(&cursors[b], hist[b]) : 0u;
    __syncthreads();

    // pass 2: scatter packed records (eid<<6 | local-node)
    for (int i = threadIdx.x; i < EPB; i += APT) {
        int e = start + i;
        if (e >= n_edges) break;
        unsigned t = tld[i];
        unsigned b = t >> BSH;
        unsigned p = base[b] + atomicAdd(&cur[b], 1u);
        if (p < (unsigned)cap)
            pairs[(size_t)b * cap + p] = ((unsigned)e << BSH) | (t & BMASK);
    }
}

__global__ __launch_bounds__(256) void bucket_reduce_kernel(
    const unsigned* __restrict__ cursors,
    const unsigned* __restrict__ pairs,
    const float4* __restrict__ edge4,
    float4* __restrict__ out_node4,
    int n_nodes, int cap)
{
    __shared__ float acc[64 * 9];
    for (int j = threadIdx.x; j < 64 * 9; j += 256) acc[j] = 0.0f;
    __syncthreads();

    const int b = blockIdx.x;
    int count = (int)cursors[b];
    if (count > cap) count = cap;
    const unsigned* pb = pairs + (size_t)b * cap;

    for (int i = threadIdx.x; i < count; i += 256) {
        unsigned pr  = pb[i];
        unsigned eid = pr >> BSH;
        unsigned loc = pr & BMASK;
        float4 d0 = edge4[(size_t)eid * 2 + 0];
        float4 d1 = edge4[(size_t)eid * 2 + 1];
        float* a = acc + loc * 9;
        atomicAdd(a + 0, d0.x);
        atomicAdd(a + 1, d0.y);
        atomicAdd(a + 2, d0.z);
        atomicAdd(a + 3, d0.w);
        atomicAdd(a + 4, d1.x);
        atomicAdd(a + 5, d1.y);
        atomicAdd(a + 6, d1.z);
        atomicAdd(a + 7, d1.w);
        atomicAdd(a + 8, 1.0f);
    }
    __syncthreads();

    // epilogue: divide by count and write final node rows (2 float4 per node)
    if (threadIdx.x < 128) {
        int loc  = threadIdx.x >> 1;
        int half = threadIdx.x & 1;
        int node = (b << BSH) + loc;
        if (node < n_nodes) {
            const float* a = acc + loc * 9;
            float inv = 1.0f / fmaxf(a[8], 1.0f);
            float4 o = { a[half * 4 + 0] * inv, a[half * 4 + 1] * inv,
                         a[half * 4 + 2] * inv, a[half * 4 + 3] * inv };
            out_node4[(size_t)node * 2 + half] = o;
        }
    }
}

// ---------------- fallback path (proven round-2 atomic version) ----------------

__global__ void fb_zero_kernel(float* __restrict__ node_out, int n_node_f,
                               float* __restrict__ counts, int n_counts) {
    int stride = gridDim.x * blockDim.x;
    int tid = blockIdx.x * blockDim.x + threadIdx.x;
    for (int i = tid; i < n_node_f; i += stride) node_out[i] = 0.0f;
    for (int i = tid; i < n_counts; i += stride) counts[i] = 0.0f;
}

__global__ void fb_edge_kernel(const float4* __restrict__ x4,
                               const int* __restrict__ src_idx,
                               const int* __restrict__ dst_idx,
                               const float4* __restrict__ ea4,
                               float4* __restrict__ out_edge4,
                               float* __restrict__ node_sums,
                               float* __restrict__ counts,
                               int n_edges) {
    int e = blockIdx.x * blockDim.x + threadIdx.x;
    if (e >= n_edges) return;
    int s = src_idx[e];
    int t = dst_idx[e];
    float4 xs0 = x4[(size_t)s * 2 + 0];
    float4 xs1 = x4[(size_t)s * 2 + 1];
    float4 xd0 = x4[(size_t)t * 2 + 0];
    float4 xd1 = x4[(size_t)t * 2 + 1];
    float4 a0  = ea4[(size_t)e * 2 + 0];
    float4 a1  = ea4[(size_t)e * 2 + 1];
    float4 d0, d1;
    d0.x = (xd0.x - xs0.x) / a0.x;
    d0.y = (xd0.y - xs0.y) / a0.y;
    d0.z = (xd0.z - xs0.z) / a0.z;
    d0.w = (xd0.w - xs0.w) / a0.w;
    d1.x = (xd1.x - xs1.x) / a1.x;
    d1.y = (xd1.y - xs1.y) / a1.y;
    d1.z = (xd1.z - xs1.z) / a1.z;
    d1.w = (xd1.w - xs1.w) / a1.w;
    out_edge4[(size_t)e * 2 + 0] = d0;
    out_edge4[(size_t)e * 2 + 1] = d1;
    float* sp = node_sums + (size_t)t * D;
    atomicAdd(sp + 0, d0.x);
    atomicAdd(sp + 1, d0.y);
    atomicAdd(sp + 2, d0.z);
    atomicAdd(sp + 3, d0.w);
    atomicAdd(sp + 4, d1.x);
    atomicAdd(sp + 5, d1.y);
    atomicAdd(sp + 6, d1.z);
    atomicAdd(sp + 7, d1.w);
    atomicAdd(counts + t, 1.0f);
}

__global__ void fb_node_kernel(float4* __restrict__ node4,
                               const float* __restrict__ counts,
                               int n_nodes) {
    int n = blockIdx.x * blockDim.x + threadIdx.x;
    if (n >= n_nodes) return;
    float inv = 1.0f / fmaxf(counts[n], 1.0f);
    float4 s0 = node4[(size_t)n * 2 + 0];
    float4 s1 = node4[(size_t)n * 2 + 1];
    s0.x *= inv; s0.y *= inv; s0.z *= inv; s0.w *= inv;
    s1.x *= inv; s1.y *= inv; s1.z *= inv; s1.w *= inv;
    node4[(size_t)n * 2 + 0] = s0;
    node4[(size_t)n * 2 + 1] = s1;
}

// ---------------- launch ----------------

extern "C" void kernel_launch(void* const* d_in, const int* in_sizes, int n_in,
                              void* d_out, int out_size, void* d_ws, size_t ws_size,
                              hipStream_t stream) {
    const float* x  = (const float*)d_in[0];      // [n_nodes, 8] fp32
    const int*   ei = (const int*)d_in[1];        // [2, n_edges] int32
    const float* ea = (const float*)d_in[2];      // [n_edges, 8] fp32

    const int n_nodes = in_sizes[0] / D;
    const int n_edges = in_sizes[2] / D;

    const int* src_idx = ei;
    const int* dst_idx = ei + n_edges;

    float* out_node = (float*)d_out;
    float* out_edge = out_node + (size_t)n_nodes * D;

    const int nb = (n_nodes + BMASK) >> BSH;      // 64-node buckets
    int cap = (int)(((long long)n_edges / (nb > 0 ? nb : 1) + 256) * 3 / 2);

    size_t cursors_bytes = ((size_t)nb * 4 + 255) & ~(size_t)255;
    size_t pairs_bytes   = (size_t)nb * cap * 4;
    size_t need = cursors_bytes + pairs_bytes;

    if (nb <= NBMAX && ws_size >= need) {
        unsigned* cursors = (unsigned*)d_ws;
        unsigned* pairs   = (unsigned*)((char*)d_ws + cursors_bytes);

        zero_cursors_kernel<<<(nb + 255) / 256, 256, 0, stream>>>(cursors, nb);

        int blocksA = (n_edges + EPB - 1) / EPB;  // 512 for 3.2M edges
        edge_phase_kernel<<<blocksA, APT, 0, stream>>>(
            (const float4*)x, src_idx, dst_idx, (const float4*)ea,
            (float4*)out_edge, cursors, pairs, n_edges, nb, cap);

        bucket_reduce_kernel<<<nb, 256, 0, stream>>>(
            cursors, pairs, (const float4*)out_edge, (float4*)out_node,
            n_nodes, cap);
    } else {
        // fallback: direct-atomic version (needs only n_nodes*4 bytes of ws)
        float* counts = (float*)d_ws;
        {
            int n = n_nodes * D;
            int blocks = (n + 255) / 256;
            if (blocks > 2048) blocks = 2048;
            fb_zero_kernel<<<blocks, 256, 0, stream>>>(out_node, n, counts, n_nodes);
        }
        fb_edge_kernel<<<(n_edges + 255) / 256, 256, 0, stream>>>(
            (const float4*)x, src_idx, dst_idx, (const float4*)ea,
            (float4*)out_edge, out_node, counts, n_edges);
        fb_node_kernel<<<(n_nodes + 255) / 256, 256, 0, stream>>>(
            (float4*)out_node, counts, n_nodes);
    }
}

// Round 5
// 288.874 us; speedup vs baseline: 5.0380x; 1.0101x over previous
//
#include <hip/hip_runtime.h>

#define D 8
#define BSH 6              // bucket = dst >> 6 (64 nodes per bucket)
#define BMASK 63
#define NBMAX 1600         // max buckets supported by fast path
#define EPB 6250           // edges per block in phase A (3.2M/512)
#define APT 1024           // phase-A threads per block
#define RPT 512            // phase-B threads per block

// ---------------- fast path ----------------

__global__ void zero_cursors_kernel(unsigned* __restrict__ cur, int nb) {
    int i = blockIdx.x * blockDim.x + threadIdx.x;
    if (i < nb) cur[i] = 0u;
}

__global__ __launch_bounds__(APT) void edge_phase_kernel(
    const float4* __restrict__ x4,
    const int* __restrict__ src_idx,
    const int* __restrict__ dst_idx,
    const float4* __restrict__ ea4,
    float4* __restrict__ out_edge4,
    unsigned* __restrict__ cursors,
    unsigned* __restrict__ pairs,
    int n_edges, int nb, int cap)
{
    __shared__ unsigned hist[NBMAX];
    __shared__ unsigned base[NBMAX];
    __shared__ unsigned cur[NBMAX];
    __shared__ unsigned tld[EPB];     // cached dst per edge

    for (int b = threadIdx.x; b < nb; b += APT) { hist[b] = 0u; cur[b] = 0u; }
    __syncthreads();

    const int start = blockIdx.x * EPB;
    int lim = n_edges - start;
    if (lim > EPB) lim = EPB;

    // pass 1: compute edge_deriv, write it, build LDS bucket histogram
#pragma unroll 2
    for (int i = threadIdx.x; i < lim; i += APT) {
        int e = start + i;
        int s = src_idx[e];
        int t = dst_idx[e];
        tld[i] = (unsigned)t;
        float4 xs0 = x4[(size_t)s * 2 + 0];
        float4 xs1 = x4[(size_t)s * 2 + 1];
        float4 xd0 = x4[(size_t)t * 2 + 0];
        float4 xd1 = x4[(size_t)t * 2 + 1];
        float4 a0  = ea4[(size_t)e * 2 + 0];
        float4 a1  = ea4[(size_t)e * 2 + 1];
        float4 d0, d1;
        d0.x = (xd0.x - xs0.x) / a0.x;
        d0.y = (xd0.y - xs0.y) / a0.y;
        d0.z = (xd0.z - xs0.z) / a0.z;
        d0.w = (xd0.w - xs0.w) / a0.w;
        d1.x = (xd1.x - xs1.x) / a1.x;
        d1.y = (xd1.y - xs1.y) / a1.y;
        d1.z = (xd1.z - xs1.z) / a1.z;
        d1.w = (xd1.w - xs1.w) / a1.w;
        out_edge4[(size_t)e * 2 + 0] = d0;
        out_edge4[(size_t)e * 2 + 1] = d1;
        atomicAdd(&hist[t >> BSH], 1u);
    }
    __syncthreads();

    // reserve contiguous space per bucket (1 device atomic per (block,bucket))
    for (int b = threadIdx.x; b < nb; b += APT)
        base[b] = hist[b] ? atomicAdd(&cursors[b], hist[b]) : 0u;
    __syncthreads();

    // pass 2: scatter packed records (eid<<6 | local-node)
    for (int i = threadIdx.x; i < lim; i += APT) {
        int e = start + i;
        unsigned t = tld[i];
        unsigned b = t >> BSH;
        unsigned p = base[b] + atomicAdd(&cur[b], 1u);
        if (p < (unsigned)cap)
            pairs[(size_t)b * cap + p] = ((unsigned)e << BSH) | (t & BMASK);
    }
}

__device__ __forceinline__ void acc9(float* __restrict__ acc, unsigned loc,
                                     float4 d0, float4 d1) {
    float* a = acc + loc * 9;
    atomicAdd(a + 0, d0.x);
    atomicAdd(a + 1, d0.y);
    atomicAdd(a + 2, d0.z);
    atomicAdd(a + 3, d0.w);
    atomicAdd(a + 4, d1.x);
    atomicAdd(a + 5, d1.y);
    atomicAdd(a + 6, d1.z);
    atomicAdd(a + 7, d1.w);
    atomicAdd(a + 8, 1.0f);
}

__global__ __launch_bounds__(RPT) void bucket_reduce_kernel(
    const unsigned* __restrict__ cursors,
    const unsigned* __restrict__ pairs,
    const float4* __restrict__ edge4,
    float4* __restrict__ out_node4,
    int n_nodes, int cap)
{
    __shared__ float acc[64 * 9];
    for (int j = threadIdx.x; j < 64 * 9; j += RPT) acc[j] = 0.0f;
    __syncthreads();

    const int b = blockIdx.x;
    int count = (int)cursors[b];
    if (count > cap) count = cap;
    const unsigned* pb = pairs + (size_t)b * cap;   // cap is a multiple of 4
    const uint4* pb4 = (const uint4*)pb;
    int n4 = count >> 2;

    // main: 4 records per thread per iter -> 8 independent 16B gathers in flight
    for (int i = threadIdx.x; i < n4; i += RPT) {
        uint4 pr = pb4[i];
        float4 va0 = edge4[(size_t)(pr.x >> BSH) * 2 + 0];
        float4 va1 = edge4[(size_t)(pr.x >> BSH) * 2 + 1];
        float4 vb0 = edge4[(size_t)(pr.y >> BSH) * 2 + 0];
        float4 vb1 = edge4[(size_t)(pr.y >> BSH) * 2 + 1];
        float4 vc0 = edge4[(size_t)(pr.z >> BSH) * 2 + 0];
        float4 vc1 = edge4[(size_t)(pr.z >> BSH) * 2 + 1];
        float4 vd0 = edge4[(size_t)(pr.w >> BSH) * 2 + 0];
        float4 vd1 = edge4[(size_t)(pr.w >> BSH) * 2 + 1];
        acc9(acc, pr.x & BMASK, va0, va1);
        acc9(acc, pr.y & BMASK, vb0, vb1);
        acc9(acc, pr.z & BMASK, vc0, vc1);
        acc9(acc, pr.w & BMASK, vd0, vd1);
    }
    // tail
    for (int i = (n4 << 2) + threadIdx.x; i < count; i += RPT) {
        unsigned pr = pb[i];
        float4 d0 = edge4[(size_t)(pr >> BSH) * 2 + 0];
        float4 d1 = edge4[(size_t)(pr >> BSH) * 2 + 1];
        acc9(acc, pr & BMASK, d0, d1);
    }
    __syncthreads();

    // epilogue: divide by count, write final node rows (2 float4 per node)
    if (threadIdx.x < 128) {
        int loc  = threadIdx.x >> 1;
        int half = threadIdx.x & 1;
        int node = (b << BSH) + loc;
        if (node < n_nodes) {
            const float* a = acc + loc * 9;
            float inv = 1.0f / fmaxf(a[8], 1.0f);
            float4 o = { a[half * 4 + 0] * inv, a[half * 4 + 1] * inv,
                         a[half * 4 + 2] * inv, a[half * 4 + 3] * inv };
            out_node4[(size_t)node * 2 + half] = o;
        }
    }
}

// ---------------- fallback path (proven round-2 atomic version) ----------------

__global__ void fb_zero_kernel(float* __restrict__ node_out, int n_node_f,
                               float* __restrict__ counts, int n_counts) {
    int stride = gridDim.x * blockDim.x;
    int tid = blockIdx.x * blockDim.x + threadIdx.x;
    for (int i = tid; i < n_node_f; i += stride) node_out[i] = 0.0f;
    for (int i = tid; i < n_counts; i += stride) counts[i] = 0.0f;
}

__global__ void fb_edge_kernel(const float4* __restrict__ x4,
                               const int* __restrict__ src_idx,
                               const int* __restrict__ dst_idx,
                               const float4* __restrict__ ea4,
                               float4* __restrict__ out_edge4,
                               float* __restrict__ node_sums,
                               float* __restrict__ counts,
                               int n_edges) {
    int e = blockIdx.x * blockDim.x + threadIdx.x;
    if (e >= n_edges) return;
    int s = src_idx[e];
    int t = dst_idx[e];
    float4 xs0 = x4[(size_t)s * 2 + 0];
    float4 xs1 = x4[(size_t)s * 2 + 1];
    float4 xd0 = x4[(size_t)t * 2 + 0];
    float4 xd1 = x4[(size_t)t * 2 + 1];
    float4 a0  = ea4[(size_t)e * 2 + 0];
    float4 a1  = ea4[(size_t)e * 2 + 1];
    float4 d0, d1;
    d0.x = (xd0.x - xs0.x) / a0.x;
    d0.y = (xd0.y - xs0.y) / a0.y;
    d0.z = (xd0.z - xs0.z) / a0.z;
    d0.w = (xd0.w - xs0.w) / a0.w;
    d1.x = (xd1.x - xs1.x) / a1.x;
    d1.y = (xd1.y - xs1.y) / a1.y;
    d1.z = (xd1.z - xs1.z) / a1.z;
    d1.w = (xd1.w - xs1.w) / a1.w;
    out_edge4[(size_t)e * 2 + 0] = d0;
    out_edge4[(size_t)e * 2 + 1] = d1;
    float* sp = node_sums + (size_t)t * D;
    atomicAdd(sp + 0, d0.x);
    atomicAdd(sp + 1, d0.y);
    atomicAdd(sp + 2, d0.z);
    atomicAdd(sp + 3, d0.w);
    atomicAdd(sp + 4, d1.x);
    atomicAdd(sp + 5, d1.y);
    atomicAdd(sp + 6, d1.z);
    atomicAdd(sp + 7, d1.w);
    atomicAdd(counts + t, 1.0f);
}

__global__ void fb_node_kernel(float4* __restrict__ node4,
                               const float* __restrict__ counts,
                               int n_nodes) {
    int n = blockIdx.x * blockDim.x + threadIdx.x;
    if (n >= n_nodes) return;
    float inv = 1.0f / fmaxf(counts[n], 1.0f);
    float4 s0 = node4[(size_t)n * 2 + 0];
    float4 s1 = node4[(size_t)n * 2 + 1];
    s0.x *= inv; s0.y *= inv; s0.z *= inv; s0.w *= inv;
    s1.x *= inv; s1.y *= inv; s1.z *= inv; s1.w *= inv;
    node4[(size_t)n * 2 + 0] = s0;
    node4[(size_t)n * 2 + 1] = s1;
}

// ---------------- launch ----------------

extern "C" void kernel_launch(void* const* d_in, const int* in_sizes, int n_in,
                              void* d_out, int out_size, void* d_ws, size_t ws_size,
                              hipStream_t stream) {
    const float* x  = (const float*)d_in[0];      // [n_nodes, 8] fp32
    const int*   ei = (const int*)d_in[1];        // [2, n_edges] int32
    const float* ea = (const float*)d_in[2];      // [n_edges, 8] fp32

    const int n_nodes = in_sizes[0] / D;
    const int n_edges = in_sizes[2] / D;

    const int* src_idx = ei;
    const int* dst_idx = ei + n_edges;

    float* out_node = (float*)d_out;
    float* out_edge = out_node + (size_t)n_nodes * D;

    const int nb = (n_nodes + BMASK) >> BSH;      // 64-node buckets
    int cap = (int)(((long long)n_edges / (nb > 0 ? nb : 1) + 256) * 3 / 2);
    cap = (cap + 3) & ~3;                          // uint4-aligned bucket rows

    size_t cursors_bytes = ((size_t)nb * 4 + 255) & ~(size_t)255;
    size_t pairs_bytes   = (size_t)nb * cap * 4;
    size_t need = cursors_bytes + pairs_bytes;

    if (nb <= NBMAX && ws_size >= need) {
        unsigned* cursors = (unsigned*)d_ws;
        unsigned* pairs   = (unsigned*)((char*)d_ws + cursors_bytes);

        zero_cursors_kernel<<<(nb + 255) / 256, 256, 0, stream>>>(cursors, nb);

        int blocksA = (n_edges + EPB - 1) / EPB;  // 512 for 3.2M edges
        edge_phase_kernel<<<blocksA, APT, 0, stream>>>(
            (const float4*)x, src_idx, dst_idx, (const float4*)ea,
            (float4*)out_edge, cursors, pairs, n_edges, nb, cap);

        bucket_reduce_kernel<<<nb, RPT, 0, stream>>>(
            cursors, pairs, (const float4*)out_edge, (float4*)out_node,
            n_nodes, cap);
    } else {
        // fallback: direct-atomic version (needs only n_nodes*4 bytes of ws)
        float* counts = (float*)d_ws;
        {
            int n = n_nodes * D;
            int blocks = (n + 255) / 256;
            if (blocks > 2048) blocks = 2048;
            fb_zero_kernel<<<blocks, 256, 0, stream>>>(out_node, n, counts, n_nodes);
        }
        fb_edge_kernel<<<(n_edges + 255) / 256, 256, 0, stream>>>(
            (const float4*)x, src_idx, dst_idx, (const float4*)ea,
            (float4*)out_edge, out_node, counts, n_edges);
        fb_node_kernel<<<(n_nodes + 255) / 256, 256, 0, stream>>>(
            (float4*)out_node, counts, n_nodes);
    }
}